// Round 3
// baseline (343.295 us; speedup 1.0000x reference)
//
#include <hip/hip_runtime.h>
#include <stdint.h>

// ---------------------------------------------------------------------------
// AdjCompute: adj = |x[n]-x[m]| (64ch) -> 4x (1x1 conv + BN(train) + lrelu)
// -> 1x1 conv -> out[1536,1536].
//
// R2 pipeline (store only h1 and h3; recompute h2/h4 where needed):
//   k_prep     : zero stats, transpose W2..W4
//   k_layer1   : MFMA, write h1 (bf16, 75.5MB) + stats1
//   k_bnprep   : stats1 -> bn1 (scale/shift)
//   k_stats<16,16> : read h1 -> h2 -> stats2 (no write)
//   k_bnprep   : stats2 -> bn2
//   k_fuse3    : read h1 -> h2 -> h3, write h3 (bf16, 37.7MB) + stats3
//   k_bnprep   : stats3 -> bn3
//   k_stats<8,8>   : read h3 -> h4 -> stats4 (no write)
//   k_bnprep   : stats4 -> bn4
//   k_last     : read h3 -> h4 -> out (fp32, 9.4MB)
//
// ws layout (floats):
//   [0..32)   stats1 (sum[16], sumsq[16])
//   [32..64)  stats2
//   [64..80)  stats3 (8+8)
//   [80..96)  stats4 (8+8)
//   [1152..1408) wt2 [16][16]  (c-major)
//   [1408..1536) wt3 [16][8]
//   [1536..1600) wt4 [8][8]
//   [1664..1728) bn1 (scale[0..16), shift[32..32+16))
//   [1728..1792) bn2
//   [1792..1856) bn3
//   [1856..1920) bn4
//   byte 8192:              bufA  h1: NN*16 bf16 = 75,497,472 B
//   byte 8192 + 75497472:   bufB  h3: NN*8  bf16 = 37,748,736 B
// ---------------------------------------------------------------------------

#define NPTS 1536
#define NN   2359296u   // 1536*1536

static constexpr float EPS   = 1e-5f;
static constexpr float SLOPE = 0.01f;
static constexpr float INV_M = 1.0f / 2359296.0f;

typedef __attribute__((ext_vector_type(8))) short bf16x8;
typedef __attribute__((ext_vector_type(4))) float f32x4;
union frag8 { int4 i; bf16x8 v; };

__device__ __forceinline__ float bflo(unsigned u) {
    return __builtin_bit_cast(float, u << 16);
}
__device__ __forceinline__ float bfhi(unsigned u) {
    return __builtin_bit_cast(float, u & 0xffff0000u);
}
__device__ __forceinline__ unsigned short f2bf(float f) {   // RNE
    unsigned u = __builtin_bit_cast(unsigned, f);
    u += 0x7fffu + ((u >> 16) & 1u);
    return (unsigned short)(u >> 16);
}
__device__ __forceinline__ unsigned pack2(float lo, float hi) {  // RNE pair
    return (unsigned)f2bf(lo) | ((unsigned)f2bf(hi) << 16);
}
// truncation pack (MFMA A-fragment inputs only; |err| <= 2^-8 rel)
__device__ __forceinline__ unsigned packtr(float lo, float hi) {
    unsigned a = __builtin_bit_cast(unsigned, lo);
    unsigned b = __builtin_bit_cast(unsigned, hi);
    return (a >> 16) | (b & 0xffff0000u);
}
__device__ __forceinline__ float lrelu(float t) {
    return fmaxf(t, t * SLOPE);
}

template <int NCH>
__device__ __forceinline__ void block_stats(float* sum, float* ssq,
                                            float* __restrict__ gstats) {
#pragma unroll
    for (int o = 0; o < NCH; o++) {
        float s = sum[o], q = ssq[o];
#pragma unroll
        for (int off = 32; off > 0; off >>= 1) {
            s += __shfl_down(s, off, 64);
            q += __shfl_down(q, off, 64);
        }
        sum[o] = s; ssq[o] = q;
    }
    __shared__ float red[4][2 * NCH];
    int wv = threadIdx.x >> 6, ln = threadIdx.x & 63;
    if (ln == 0) {
#pragma unroll
        for (int o = 0; o < NCH; o++) {
            red[wv][o]       = sum[o];
            red[wv][NCH + o] = ssq[o];
        }
    }
    __syncthreads();
    if (threadIdx.x < 2 * NCH) {
        float v = red[0][threadIdx.x] + red[1][threadIdx.x] +
                  red[2][threadIdx.x] + red[3][threadIdx.x];
        atomicAdd(gstats + threadIdx.x, v);
    }
}

__global__ __launch_bounds__(256) void k_prep(
        const float* __restrict__ W2, const float* __restrict__ W3,
        const float* __restrict__ W4, float* __restrict__ ws) {
    int t = threadIdx.x;
    if (t < 96) ws[t] = 0.0f;
    { int o = t >> 4, c = t & 15; ws[1152 + c * 16 + o] = W2[t]; }
    if (t < 128) { int o = t >> 4, c = t & 15; ws[1408 + c * 8 + o] = W3[t]; }
    if (t < 64)  { int o = t >> 3, c = t & 7;  ws[1536 + c * 8 + o] = W4[t]; }
}

// stats[c]=sum, stats[CI+c]=sumsq -> bn[c]=scale, bn[32+c]=shift
__global__ __launch_bounds__(64) void k_bnprep(
        const float* __restrict__ stats, const float* __restrict__ g,
        const float* __restrict__ be, int CI, float* __restrict__ bn) {
    int c = threadIdx.x;
    if (c < CI) {
        float mu  = stats[c] * INV_M;
        float var = fmaf(-mu, mu, stats[CI + c] * INV_M);
        float sc  = g[c] * rsqrtf(var + EPS);
        bn[c]      = sc;
        bn[32 + c] = fmaf(-mu, sc, be[c]);
    }
}

// Layer 1 (MFMA): h1[n, m, o] = b1[o] + sum_c W1[o,c] * |x[m,c]-x[n,c]|
// wave = 16 m x 16 o x 1 n; 24 n's per wave; grid 1536 blocks (6144 waves).
__global__ __launch_bounds__(256) void k_layer1(
        const float* __restrict__ x, const float* __restrict__ W1,
        const float* __restrict__ b1, unsigned short* __restrict__ outb,
        float* __restrict__ stats) {
    int lane = threadIdx.x & 63;
    int wv   = threadIdx.x >> 6;
    int gid  = blockIdx.x * 4 + wv;
    int mt   = gid % 96;          // m-tile
    int nc   = gid / 96;          // n-chunk 0..63
    int o    = lane & 15;
    int quad = lane >> 4;
    int cb   = quad * 8;

    // B fragments: B[k=cb+j][o] = W1[o][cb+j]  (RNE, one-time)
    const float* wr = W1 + o * 64 + cb;
    float4 w0 = *(const float4*)(wr);
    float4 w1 = *(const float4*)(wr + 4);
    float4 w2 = *(const float4*)(wr + 32);
    float4 w3 = *(const float4*)(wr + 36);
    frag8 fb1, fb2;
    fb1.i = make_int4(pack2(w0.x, w0.y), pack2(w0.z, w0.w),
                      pack2(w1.x, w1.y), pack2(w1.z, w1.w));
    fb2.i = make_int4(pack2(w2.x, w2.y), pack2(w2.z, w2.w),
                      pack2(w3.x, w3.y), pack2(w3.z, w3.w));

    const float* xr = x + (mt * 16 + o) * 64 + cb;
    float4 xa0 = *(const float4*)(xr);
    float4 xa1 = *(const float4*)(xr + 4);
    float4 xa2 = *(const float4*)(xr + 32);
    float4 xa3 = *(const float4*)(xr + 36);

    float bias = b1[o];
    float lsum = 0.f, lssq = 0.f;
    unsigned mrow = mt * 16 + quad * 4;

    int n0 = nc * 24;
    const float* xp = x + (size_t)n0 * 64 + cb;
    float4 uA0 = *(const float4*)(xp);
    float4 uA1 = *(const float4*)(xp + 4);
    float4 uA2 = *(const float4*)(xp + 32);
    float4 uA3 = *(const float4*)(xp + 36);
    const float* xq = x + (size_t)(n0 + 1) * 64 + cb;
    float4 uB0 = *(const float4*)(xq);
    float4 uB1 = *(const float4*)(xq + 4);
    float4 uB2 = *(const float4*)(xq + 32);
    float4 uB3 = *(const float4*)(xq + 36);

    auto body = [&](int n, float4& u0, float4& u1, float4& u2, float4& u3,
                    int pf) {
        // build A fragments (truncation pack)
        frag8 fa1, fa2;
        fa1.i = make_int4(
            packtr(fabsf(xa0.x - u0.x), fabsf(xa0.y - u0.y)),
            packtr(fabsf(xa0.z - u0.z), fabsf(xa0.w - u0.w)),
            packtr(fabsf(xa1.x - u1.x), fabsf(xa1.y - u1.y)),
            packtr(fabsf(xa1.z - u1.z), fabsf(xa1.w - u1.w)));
        fa2.i = make_int4(
            packtr(fabsf(xa2.x - u2.x), fabsf(xa2.y - u2.y)),
            packtr(fabsf(xa2.z - u2.z), fabsf(xa2.w - u2.w)),
            packtr(fabsf(xa3.x - u3.x), fabsf(xa3.y - u3.y)),
            packtr(fabsf(xa3.z - u3.z), fabsf(xa3.w - u3.w)));
        // prefetch (overwrites u regs; last uses above)
        const float* xf = x + (size_t)pf * 64 + cb;
        u0 = *(const float4*)(xf);
        u1 = *(const float4*)(xf + 4);
        u2 = *(const float4*)(xf + 32);
        u3 = *(const float4*)(xf + 36);
        f32x4 acc = {bias, bias, bias, bias};
        acc = __builtin_amdgcn_mfma_f32_16x16x32_bf16(fa1.v, fb1.v, acc, 0, 0, 0);
        acc = __builtin_amdgcn_mfma_f32_16x16x32_bf16(fa2.v, fb2.v, acc, 0, 0, 0);
        size_t base = ((size_t)n * NPTS + mrow) * 16 + o;
#pragma unroll
        for (int r = 0; r < 4; r++) {
            float v = acc[r];
            lsum += v;
            lssq = fmaf(v, v, lssq);
            outb[base + (unsigned)r * 16u] = f2bf(v);
        }
    };

#pragma unroll 1
    for (int i = 0; i < 24; i += 2) {
        int pfA = n0 + ((i + 2 < 24) ? i + 2 : 23);
        int pfB = n0 + ((i + 3 < 24) ? i + 3 : 23);
        body(n0 + i,     uA0, uA1, uA2, uA3, pfA);
        body(n0 + i + 1, uB0, uB1, uB2, uB3, pfB);
    }

    // wave reduce over quads, then block reduce, then atomics
    lsum += __shfl_xor(lsum, 16); lssq += __shfl_xor(lssq, 16);
    lsum += __shfl_xor(lsum, 32); lssq += __shfl_xor(lssq, 32);
    __shared__ float red[4][32];
    if (quad == 0) { red[wv][o] = lsum; red[wv][16 + o] = lssq; }
    __syncthreads();
    if (threadIdx.x < 32) {
        float v = red[0][threadIdx.x] + red[1][threadIdx.x] +
                  red[2][threadIdx.x] + red[3][threadIdx.x];
        atomicAdd(stats + threadIdx.x, v);
    }
}

template <int CI>
__device__ __forceinline__ void unpack_bn(const uint4* v, const float* bn,
                                          float* a) {
#pragma unroll
    for (int q = 0; q < CI / 8; q++) {
        uint4 w = v[q];
        a[8*q+0] = bflo(w.x); a[8*q+1] = bfhi(w.x);
        a[8*q+2] = bflo(w.y); a[8*q+3] = bfhi(w.y);
        a[8*q+4] = bflo(w.z); a[8*q+5] = bfhi(w.z);
        a[8*q+6] = bflo(w.w); a[8*q+7] = bfhi(w.w);
    }
#pragma unroll
    for (int c = 0; c < CI; c++)
        a[c] = lrelu(fmaf(a[c], bn[c], bn[32 + c]));
}

// stats-only layer: read h_pre, BN+lrelu, matmul, accumulate stats (no write)
template <int CI, int CO>
__global__ __launch_bounds__(256) void k_stats(
        const uint4* __restrict__ inb, const float* __restrict__ bn,
        const float* __restrict__ wt, const float* __restrict__ b,
        float* __restrict__ statsOut) {
    float sum[CO], ssq[CO];
#pragma unroll
    for (int o = 0; o < CO; o++) { sum[o] = 0.f; ssq[o] = 0.f; }
    unsigned base = blockIdx.x * 2048u + threadIdx.x;
#pragma unroll 1
    for (int j = 0; j < 4; j++) {
        size_t p1 = base + (unsigned)j * 512u;
        size_t p2 = p1 + 256u;
        uint4 va[CI / 8], vb[CI / 8];
        const uint4* s1 = inb + p1 * (CI / 8);
        const uint4* s2 = inb + p2 * (CI / 8);
#pragma unroll
        for (int q = 0; q < CI / 8; q++) { va[q] = s1[q]; vb[q] = s2[q]; }
#pragma unroll
        for (int half = 0; half < 2; half++) {
            float a[CI];
            unpack_bn<CI>(half ? vb : va, bn, a);
            float acc[CO];
#pragma unroll
            for (int o = 0; o < CO; o++) acc[o] = b[o];
#pragma unroll
            for (int c = 0; c < CI; c++)
#pragma unroll
                for (int o = 0; o < CO; o++)
                    acc[o] = fmaf(a[c], wt[c * CO + o], acc[o]);
#pragma unroll
            for (int o = 0; o < CO; o++) {
                sum[o] += acc[o];
                ssq[o] = fmaf(acc[o], acc[o], ssq[o]);
            }
        }
    }
    block_stats<CO>(sum, ssq, statsOut);
}

// fused h1 -> act1 -> h2 -> act2 -> h3 ; writes h3 (8ch bf16) + stats3
__global__ __launch_bounds__(256) void k_fuse3(
        const uint4* __restrict__ inb, uint4* __restrict__ outb,
        const float* __restrict__ bn1, const float* __restrict__ wt2,
        const float* __restrict__ b2, const float* __restrict__ bn2,
        const float* __restrict__ wt3, const float* __restrict__ b3,
        float* __restrict__ stats3) {
    float sum[8], ssq[8];
#pragma unroll
    for (int o = 0; o < 8; o++) { sum[o] = 0.f; ssq[o] = 0.f; }
    unsigned base = blockIdx.x * 2048u + threadIdx.x;
#pragma unroll 1
    for (int j = 0; j < 4; j++) {
        size_t p1 = base + (unsigned)j * 512u;
        size_t p2 = p1 + 256u;
        uint4 va[2], vb[2];
        const uint4* s1 = inb + p1 * 2;
        const uint4* s2 = inb + p2 * 2;
        va[0] = s1[0]; va[1] = s1[1];
        vb[0] = s2[0]; vb[1] = s2[1];
#pragma unroll
        for (int half = 0; half < 2; half++) {
            float a[16];
            unpack_bn<16>(half ? vb : va, bn1, a);
            float h2[16];
#pragma unroll
            for (int o = 0; o < 16; o++) h2[o] = b2[o];
#pragma unroll
            for (int c = 0; c < 16; c++)
#pragma unroll
                for (int o = 0; o < 16; o++)
                    h2[o] = fmaf(a[c], wt2[c * 16 + o], h2[o]);
#pragma unroll
            for (int c = 0; c < 16; c++)
                h2[c] = lrelu(fmaf(h2[c], bn2[c], bn2[32 + c]));
            float h3[8];
#pragma unroll
            for (int o = 0; o < 8; o++) h3[o] = b3[o];
#pragma unroll
            for (int c = 0; c < 16; c++)
#pragma unroll
                for (int o = 0; o < 8; o++)
                    h3[o] = fmaf(h2[c], wt3[c * 8 + o], h3[o]);
#pragma unroll
            for (int o = 0; o < 8; o++) {
                sum[o] += h3[o];
                ssq[o] = fmaf(h3[o], h3[o], ssq[o]);
            }
            outb[half ? p2 : p1] =
                make_uint4(pack2(h3[0], h3[1]), pack2(h3[2], h3[3]),
                           pack2(h3[4], h3[5]), pack2(h3[6], h3[7]));
        }
    }
    block_stats<8>(sum, ssq, stats3);
}

// final: read h3, act3, h4 = W4*act3+b4, act4, out = W5*act4 + b5
__global__ __launch_bounds__(256) void k_last(
        const uint4* __restrict__ inb, const float* __restrict__ bn3,
        const float* __restrict__ wt4, const float* __restrict__ b4,
        const float* __restrict__ bn4, const float* __restrict__ W5,
        const float* __restrict__ b5, float* __restrict__ out) {
    unsigned p = blockIdx.x * 256u + threadIdx.x;
    uint4 v = inb[p];
    float a[8];
    a[0] = bflo(v.x); a[1] = bfhi(v.x);
    a[2] = bflo(v.y); a[3] = bfhi(v.y);
    a[4] = bflo(v.z); a[5] = bfhi(v.z);
    a[6] = bflo(v.w); a[7] = bfhi(v.w);
#pragma unroll
    for (int c = 0; c < 8; c++)
        a[c] = lrelu(fmaf(a[c], bn3[c], bn3[32 + c]));
    float h4[8];
#pragma unroll
    for (int o = 0; o < 8; o++) h4[o] = b4[o];
#pragma unroll
    for (int c = 0; c < 8; c++)
#pragma unroll
        for (int o = 0; o < 8; o++)
            h4[o] = fmaf(a[c], wt4[c * 8 + o], h4[o]);
    float acc = b5[0];
#pragma unroll
    for (int c = 0; c < 8; c++) {
        float t = lrelu(fmaf(h4[c], bn4[c], bn4[32 + c]));
        acc = fmaf(t, W5[c], acc);
    }
    out[p] = acc;
}

extern "C" void kernel_launch(void* const* d_in, const int* in_sizes, int n_in,
                              void* d_out, int out_size, void* d_ws,
                              size_t ws_size, hipStream_t stream) {
    const float* x   = (const float*)d_in[0];
    const float* W1  = (const float*)d_in[1];
    const float* b1  = (const float*)d_in[2];
    const float* g1  = (const float*)d_in[3];
    const float* be1 = (const float*)d_in[4];
    const float* W2  = (const float*)d_in[5];
    const float* b2  = (const float*)d_in[6];
    const float* g2  = (const float*)d_in[7];
    const float* be2 = (const float*)d_in[8];
    const float* W3  = (const float*)d_in[9];
    const float* b3  = (const float*)d_in[10];
    const float* g3  = (const float*)d_in[11];
    const float* be3 = (const float*)d_in[12];
    const float* W4  = (const float*)d_in[13];
    const float* b4  = (const float*)d_in[14];
    const float* g4  = (const float*)d_in[15];
    const float* be4 = (const float*)d_in[16];
    const float* W5  = (const float*)d_in[17];
    const float* b5  = (const float*)d_in[18];

    float* ws     = (float*)d_ws;
    float* stats1 = ws + 0;
    float* stats2 = ws + 32;
    float* stats3 = ws + 64;
    float* stats4 = ws + 80;
    float* wt2    = ws + 1152;
    float* wt3    = ws + 1408;
    float* wt4    = ws + 1536;
    float* bn1    = ws + 1664;
    float* bn2    = ws + 1728;
    float* bn3    = ws + 1792;
    float* bn4    = ws + 1856;
    unsigned short* bufA = (unsigned short*)((char*)d_ws + 8192);
    uint4* bufB = (uint4*)((char*)d_ws + 8192 + (size_t)NN * 32u);

    k_prep<<<1, 256, 0, stream>>>(W2, W3, W4, ws);
    k_layer1<<<1536, 256, 0, stream>>>(x, W1, b1, bufA, stats1);
    k_bnprep<<<1, 64, 0, stream>>>(stats1, g1, be1, 16, bn1);
    k_stats<16, 16><<<1152, 256, 0, stream>>>((const uint4*)bufA, bn1,
                                              wt2, b2, stats2);
    k_bnprep<<<1, 64, 0, stream>>>(stats2, g2, be2, 16, bn2);
    k_fuse3<<<1152, 256, 0, stream>>>((const uint4*)bufA, bufB,
                                      bn1, wt2, b2, bn2, wt3, b3, stats3);
    k_bnprep<<<1, 64, 0, stream>>>(stats3, g3, be3, 8, bn3);
    k_stats<8, 8><<<1152, 256, 0, stream>>>((const uint4*)bufB, bn3,
                                            wt4, b4, stats4);
    k_bnprep<<<1, 64, 0, stream>>>(stats4, g4, be4, 8, bn4);
    k_last<<<9216, 256, 0, stream>>>((const uint4*)bufB, bn3, wt4, b4,
                                     bn4, W5, b5, (float*)d_out);
}